// Round 1
// baseline (4301.090 us; speedup 1.0000x reference)
//
#include <hip/hip_runtime.h>

// ---------------------------------------------------------------------------
// 2-layer bidirectional GRU, H=256, C=512, T=512, B=64  (MI355X / gfx950)
//
// Pipeline (stream-ordered):
//   1) k_transpose: x fp32 [b][c][t] -> xT bf16 [b][t][c]         (ws region A)
//   2) k_gemm:      xp[d][b][t][g] = xT @ w_ih[d]^T + b_ih[d] (+b_hh r,z fold)
//                   bf16 MFMA 16x16x32, N = 2*768 (both dirs)     (ws region B)
//   3) k_rec<bf16>: layer-0 recurrence -> y0 bf16 [b][t][512]     (ws region A)
//   4) k_gemm:      xp = y0 @ w_ih_l1^T + bias fold               (ws region B)
//   5) k_rec<f32>:  layer-1 recurrence -> d_out fp32
//
// Recurrence: one 512-thread WG per (dir, batch-block-of-16) = 8 WGs.
// W_hh lives in MFMA B-fragments in registers (192 VGPR/lane, persistent).
// h: fp32 master in regs, bf16 copy in LDS (double buffered) feeds MFMA A.
// xp step tile staged to LDS one step ahead (double buffered). 1 barrier/step.
// ---------------------------------------------------------------------------

typedef unsigned short u16;
typedef __attribute__((ext_vector_type(8))) short short8;   // 8 bf16 = 4 VGPR
typedef __attribute__((ext_vector_type(4))) float f32x4;

static __device__ __forceinline__ u16 f2bf(float x){
  union { float f; unsigned u; } v; v.f = x;
  unsigned r = v.u + 0x7fffu + ((v.u >> 16) & 1u);   // RNE
  return (u16)(r >> 16);
}
static __device__ __forceinline__ float bf2f(u16 b){
  union { float f; unsigned u; } v; v.u = ((unsigned)b) << 16;
  return v.f;
}
static __device__ __forceinline__ float sigm(float x){ return 1.0f / (1.0f + __expf(-x)); }
static __device__ __forceinline__ float tanhfast(float x){ return 2.0f / (1.0f + __expf(-2.0f * x)) - 1.0f; }

#define TT 512   // sequence length
#define BB 64    // batch
#define HH 256   // hidden
#define GG 768   // 3*H
#define CC 512   // input channels (both layers)

// ---------------------------------------------------------------------------
// 1) transpose + cast: x fp32 [B][C][T] -> xT bf16 [B][T][C]
// ---------------------------------------------------------------------------
__global__ __launch_bounds__(256) void k_transpose(const float* __restrict__ x,
                                                   u16* __restrict__ xT)
{
  __shared__ u16 tile[32][33];
  const int b  = blockIdx.z;
  const int c0 = blockIdx.y * 32, t0 = blockIdx.x * 32;
  const int tx = threadIdx.x & 31, ty = threadIdx.x >> 5;   // ty 0..7
  const float* xb = x + (size_t)b * CC * TT;
  #pragma unroll
  for (int i = 0; i < 4; ++i){
    int c = c0 + ty + i * 8;
    tile[ty + i * 8][tx] = f2bf(xb[(size_t)c * TT + t0 + tx]);
  }
  __syncthreads();
  u16* o = xT + (size_t)b * TT * CC;
  #pragma unroll
  for (int i = 0; i < 4; ++i){
    int t = t0 + ty + i * 8;
    o[(size_t)t * CC + c0 + tx] = tile[tx][ty + i * 8];
  }
}

// ---------------------------------------------------------------------------
// 2) GEMM: xp[d][b][t][gg] = sum_k A[(b,t)][k] * W_d[gg][k] + bias
//    A bf16 [32768][512]; W fp32 [768][512] per dir; N-dim = 1536 (2 dirs).
//    bias = b_ih[gg] + (gg<512 ? b_hh[gg] : 0)   (r,z b_hh folded; n not)
//    64x64 tile, BK=64, 4 waves, MFMA 16x16x32 bf16.
// ---------------------------------------------------------------------------
__global__ __launch_bounds__(256) void k_gemm(const u16* __restrict__ A,
    const float* __restrict__ wf, const float* __restrict__ wr,
    const float* __restrict__ bif, const float* __restrict__ bir,
    const float* __restrict__ bhf, const float* __restrict__ bhr,
    u16* __restrict__ xp)
{
  __shared__ u16 As[64][72];   // +8 u16 pad: 144B row, 2-way bank alias (free)
  __shared__ u16 Bs[64][72];
  const int tid = threadIdx.x;
  const int n0  = blockIdx.x * 64;          // 0..1535, never straddles dirs
  const int m0  = blockIdx.y * 64;
  const int dir = (n0 >= GG) ? 1 : 0;
  const int gb  = n0 - dir * GG;
  const float* W  = dir ? wr : wf;
  const float* BI = dir ? bir : bif;
  const float* BH = dir ? bhr : bhf;

  const int w = tid >> 6, l = tid & 63, q = l >> 4, r = l & 15;
  f32x4 acc[4] = {};

  for (int k0 = 0; k0 < CC; k0 += 64){
    #pragma unroll
    for (int i = 0; i < 2; ++i){            // A: 64x64 bf16, 16B per thread-chunk
      int ch = tid + 256 * i;               // 0..511
      int row = ch >> 3, c8 = ch & 7;
      *(uint4*)&As[row][c8 * 8] =
          *(const uint4*)&A[(size_t)(m0 + row) * CC + k0 + c8 * 8];
    }
    #pragma unroll
    for (int i = 0; i < 4; ++i){            // B: 64x64 fp32 -> bf16
      int ch = tid + 256 * i;               // 0..1023
      int row = ch >> 4, c4 = ch & 15;
      const float* s = &W[(size_t)(gb + row) * CC + k0 + c4 * 4];
      float4 fv = *(const float4*)s;
      unsigned p0 = (unsigned)f2bf(fv.x) | ((unsigned)f2bf(fv.y) << 16);
      unsigned p1 = (unsigned)f2bf(fv.z) | ((unsigned)f2bf(fv.w) << 16);
      *(uint2*)&Bs[row][c4 * 4] = make_uint2(p0, p1);
    }
    __syncthreads();
    #pragma unroll
    for (int kk = 0; kk < 2; ++kk){
      short8 a = *(const short8*)&As[w * 16 + r][kk * 32 + q * 8];
      #pragma unroll
      for (int nt = 0; nt < 4; ++nt){
        short8 b = *(const short8*)&Bs[nt * 16 + r][kk * 32 + q * 8];
        acc[nt] = __builtin_amdgcn_mfma_f32_16x16x32_bf16(a, b, acc[nt], 0, 0, 0);
      }
    }
    __syncthreads();
  }
  // epilogue: C/D layout col = lane&15, row = (lane>>4)*4 + j
  #pragma unroll
  for (int nt = 0; nt < 4; ++nt){
    int gg = gb + nt * 16 + r;
    float bias = BI[gg] + (gg < 2 * HH ? BH[gg] : 0.0f);
    #pragma unroll
    for (int j = 0; j < 4; ++j){
      int m = m0 + w * 16 + q * 4 + j;      // m = b*T + t (T=512 divides tiles)
      int b = m >> 9, t = m & 511;
      xp[(((size_t)dir * BB + b) * TT + t) * GG + gg] = f2bf(acc[nt][j] + bias);
    }
  }
}

// ---------------------------------------------------------------------------
// 3/5) recurrence. grid = 8: blockIdx = dir*4 + batch_block. 512 threads.
// wave wv owns h-cols [32*wv, 32*wv+32) for ALL three gates (r,z,n aligned
// per-lane -> gate combine fully in-register, no exchange).
// ---------------------------------------------------------------------------
template<int OUT_F32>
__global__ __launch_bounds__(512, 2) void k_rec(const u16* __restrict__ xp,
    const float* __restrict__ whf, const float* __restrict__ whr,
    const float* __restrict__ bhf, const float* __restrict__ bhr,
    void* __restrict__ yout)
{
  __shared__ u16 hl[2][16][264];     // h bf16, 528B row: 2-way bank alias only
  __shared__ u16 xps[2][16][GG];     // xp step tile, double buffered
  const int tid = threadIdx.x;
  const int d  = blockIdx.x >> 2, bb = blockIdx.x & 3;
  const int wv = tid >> 6, l = tid & 63, q = l >> 4, r = l & 15;
  const float* WH = d ? whr : whf;
  const float* BH = d ? bhr : bhf;
  const int b0 = bb * 16;

  // persistent W_hh B-fragments: gh[m][g] = sum_k h[m][k]*W[g][k]
  // B-frag: lane supplies B[k=(kk*32+q*8+e)][g=colbase+r] = W[g][k]
  short8 Bf[3][2][8];                          // 192 VGPR, lives whole kernel
  #pragma unroll
  for (int gi = 0; gi < 3; ++gi)
    #pragma unroll
    for (int ct = 0; ct < 2; ++ct){
      int g = gi * HH + wv * 32 + ct * 16 + r;
      #pragma unroll
      for (int kk = 0; kk < 8; ++kk){
        const float* s = &WH[(size_t)g * HH + kk * 32 + q * 8];
        float4 f0 = *(const float4*)s;
        float4 f1 = *(const float4*)(s + 4);
        short8 f;
        f[0]=(short)f2bf(f0.x); f[1]=(short)f2bf(f0.y);
        f[2]=(short)f2bf(f0.z); f[3]=(short)f2bf(f0.w);
        f[4]=(short)f2bf(f1.x); f[5]=(short)f2bf(f1.y);
        f[6]=(short)f2bf(f1.z); f[7]=(short)f2bf(f1.w);
        Bf[gi][ct][kk] = f;
      }
    }
  float bn[2];                                  // b_hh n-gate (inside r*(...))
  #pragma unroll
  for (int ct = 0; ct < 2; ++ct) bn[ct] = BH[2 * HH + wv * 32 + ct * 16 + r];

  float ho[2][4] = {};                          // fp32 h master (rows q*4+j)

  for (int i = tid; i < 2 * 16 * 264; i += 512) ((u16*)hl)[i] = 0;
  {                                             // stage xps[0] for step 0
    int row = tid >> 5, sub = tid & 31;
    int t0 = d ? (TT - 1) : 0;
    const u16* src = &xp[(((size_t)d * BB + b0 + row) * TT + t0) * GG];
    #pragma unroll
    for (int i = 0; i < 3; ++i)
      *(uint4*)&xps[0][row][(sub + 32 * i) * 8] = *(const uint4*)&src[(sub + 32 * i) * 8];
  }
  __syncthreads();

  u16*   yb = (u16*)yout;
  float* yf = (float*)yout;

  for (int s = 0; s < TT; ++s){
    const int cur = s & 1, nxt = cur ^ 1;
    const int t  = d ? (TT - 1 - s) : s;
    const int tn = (s < TT - 1) ? (d ? t - 1 : t + 1) : t;

    // (1) prefetch next step's xp tile into regs (consumed at step (4))
    uint4 stg[3];
    {
      int row = tid >> 5, sub = tid & 31;
      const u16* src = &xp[(((size_t)d * BB + b0 + row) * TT + tn) * GG];
      #pragma unroll
      for (int i = 0; i < 3; ++i) stg[i] = *(const uint4*)&src[(sub + 32 * i) * 8];
    }
    // (2) gh = h @ W^T  (+ b_hh_n on n-gate)
    f32x4 acc[3][2];
    #pragma unroll
    for (int ct = 0; ct < 2; ++ct){
      acc[0][ct] = (f32x4){0.f, 0.f, 0.f, 0.f};
      acc[1][ct] = (f32x4){0.f, 0.f, 0.f, 0.f};
      acc[2][ct] = (f32x4){bn[ct], bn[ct], bn[ct], bn[ct]};
    }
    #pragma unroll
    for (int kk = 0; kk < 8; ++kk){
      short8 a = *(const short8*)&hl[cur][r][kk * 32 + q * 8];
      #pragma unroll
      for (int gi = 0; gi < 3; ++gi)
        #pragma unroll
        for (int ct = 0; ct < 2; ++ct)
          acc[gi][ct] = __builtin_amdgcn_mfma_f32_16x16x32_bf16(a, Bf[gi][ct][kk], acc[gi][ct], 0, 0, 0);
    }
    // (3) gates + h update + y store (row m=q*4+j, col=wv*32+ct*16+r)
    #pragma unroll
    for (int ct = 0; ct < 2; ++ct){
      int col = wv * 32 + ct * 16 + r;
      #pragma unroll
      for (int j = 0; j < 4; ++j){
        int m = q * 4 + j;
        float xr = bf2f(xps[cur][m][col]);            // b_ih + b_hh_r folded
        float xz = bf2f(xps[cur][m][HH + col]);       // b_ih + b_hh_z folded
        float xn = bf2f(xps[cur][m][2 * HH + col]);   // b_ih only
        float rr = sigm(xr + acc[0][ct][j]);
        float zz = sigm(xz + acc[1][ct][j]);
        float nn = tanhfast(xn + rr * acc[2][ct][j]);
        float hn = (1.0f - zz) * nn + zz * ho[ct][j];
        ho[ct][j] = hn;
        hl[nxt][m][col] = f2bf(hn);
        size_t yi = (((size_t)(b0 + m) * TT + t) * (2 * HH)) + (size_t)d * HH + col;
        if (OUT_F32) yf[yi] = hn; else yb[yi] = f2bf(hn);
      }
    }
    // (4) commit prefetched xp tile to LDS
    {
      int row = tid >> 5, sub = tid & 31;
      #pragma unroll
      for (int i = 0; i < 3; ++i)
        *(uint4*)&xps[nxt][row][(sub + 32 * i) * 8] = stg[i];
    }
    __syncthreads();
  }
}

// ---------------------------------------------------------------------------
extern "C" void kernel_launch(void* const* d_in, const int* in_sizes, int n_in,
                              void* d_out, int out_size, void* d_ws, size_t ws_size,
                              hipStream_t stream)
{
  const float* x        = (const float*)d_in[0];
  const float* w_ih_l0f = (const float*)d_in[1];
  const float* w_hh_l0f = (const float*)d_in[2];
  const float* b_ih_l0f = (const float*)d_in[3];
  const float* b_hh_l0f = (const float*)d_in[4];
  const float* w_ih_l0r = (const float*)d_in[5];
  const float* w_hh_l0r = (const float*)d_in[6];
  const float* b_ih_l0r = (const float*)d_in[7];
  const float* b_hh_l0r = (const float*)d_in[8];
  const float* w_ih_l1f = (const float*)d_in[9];
  const float* w_hh_l1f = (const float*)d_in[10];
  const float* b_ih_l1f = (const float*)d_in[11];
  const float* b_hh_l1f = (const float*)d_in[12];
  const float* w_ih_l1r = (const float*)d_in[13];
  const float* w_hh_l1r = (const float*)d_in[14];
  const float* b_ih_l1r = (const float*)d_in[15];
  const float* b_hh_l1r = (const float*)d_in[16];

  // ws layout: [region A: 16.78M u16 = xT then y0] [region B: 50.33M u16 = xp]
  u16* xT = (u16*)d_ws;
  u16* xp = xT + (size_t)BB * TT * CC;
  u16* y0 = xT;                       // xT dead after layer-0 GEMM
  (void)in_sizes; (void)n_in; (void)out_size; (void)ws_size;

  k_transpose<<<dim3(TT / 32, CC / 32, BB), 256, 0, stream>>>(x, xT);

  k_gemm<<<dim3(2 * GG / 64, BB * TT / 64), 256, 0, stream>>>(
      xT, w_ih_l0f, w_ih_l0r, b_ih_l0f, b_ih_l0r, b_hh_l0f, b_hh_l0r, xp);

  k_rec<0><<<dim3(8), 512, 0, stream>>>(xp, w_hh_l0f, w_hh_l0r, b_hh_l0f, b_hh_l0r, (void*)y0);

  k_gemm<<<dim3(2 * GG / 64, BB * TT / 64), 256, 0, stream>>>(
      y0, w_ih_l1f, w_ih_l1r, b_ih_l1f, b_ih_l1r, b_hh_l1f, b_hh_l1r, xp);

  k_rec<1><<<dim3(8), 512, 0, stream>>>(xp, w_hh_l1f, w_hh_l1r, b_hh_l1f, b_hh_l1r, d_out);
}

// Round 3
// 2318.947 us; speedup vs baseline: 1.8548x; 1.8548x over previous
//
#include <hip/hip_runtime.h>

// ---------------------------------------------------------------------------
// 2-layer bidirectional GRU, H=256, C=512, T=512, B=64  (MI355X / gfx950)
//
// Row order for all GEMM activations ("row'"): row' = ((b>>4)*512 + t)*16 + (b&15)
//   -> a 64-row GEMM M-tile = 4 consecutive t x 16 batch rows (one rec block).
// xp layout (rec-native): [d][bb][t][gi][lane 512][8 u16]; each rec lane reads
//   its 24 gate inputs as 3 coalesced dwordx4 loads. No xp LDS staging.
// Recurrence: 8 WGs (dir x batch-block16), 512 thr; W_hh persistent in
//   MFMA B-fragments (192 VGPR); h fp32 in regs + bf16 LDS (double buffer);
//   raw s_barrier (lgkmcnt only) so xp prefetch stays in flight across it.
//
// R2 bug fixed here: tanh identity was sign-flipped (1-2/(1+e^-2x) = -tanh).
// Correct: tanh(x) = 2/(1+e^(-2x)) - 1.
// ---------------------------------------------------------------------------

typedef unsigned short u16;
typedef __attribute__((ext_vector_type(8))) short short8;          // 8 bf16
typedef __attribute__((ext_vector_type(8))) unsigned short ushort8;
typedef __attribute__((ext_vector_type(4))) float f32x4;

static __device__ __forceinline__ u16 f2bf(float x){
  union { float f; unsigned u; } v; v.f = x;
  unsigned r = v.u + 0x7fffu + ((v.u >> 16) & 1u);   // RNE
  return (u16)(r >> 16);
}
static __device__ __forceinline__ float bf2f(u16 b){
  union { float f; unsigned u; } v; v.u = ((unsigned)b) << 16;
  return v.f;
}

#define TT 512
#define BB 64
#define HH 256
#define GG 768
#define CC 512

// ---------------------------------------------------------------------------
// 1) transpose + cast: x fp32 [B][C][T] -> xT bf16 [row'][C]
// ---------------------------------------------------------------------------
__global__ __launch_bounds__(256) void k_transpose(const float* __restrict__ x,
                                                   u16* __restrict__ xT)
{
  __shared__ u16 tile[32][33];
  const int b  = blockIdx.z;
  const int c0 = blockIdx.y * 32, t0 = blockIdx.x * 32;
  const int tx = threadIdx.x & 31, ty = threadIdx.x >> 5;
  const float* xb = x + (size_t)b * CC * TT;
  #pragma unroll
  for (int i = 0; i < 4; ++i){
    int c = c0 + ty + i * 8;
    tile[ty + i * 8][tx] = f2bf(xb[(size_t)c * TT + t0 + tx]);
  }
  __syncthreads();
  const int bb = b >> 4, mrow = b & 15;
  #pragma unroll
  for (int i = 0; i < 4; ++i){
    int t = t0 + ty + i * 8;
    size_t rowp = ((size_t)bb * TT + t) * 16 + mrow;
    xT[rowp * CC + c0 + tx] = tile[tx][ty + i * 8];
  }
}

// ---------------------------------------------------------------------------
// 2) GEMM: A[row'][k] (bf16) x W[g][k] (fp32->bf16) -> xp rec-native layout
//    bias = b_ih[g] + (g<512 ? b_hh[g] : 0)
// ---------------------------------------------------------------------------
__global__ __launch_bounds__(256) void k_gemm(const u16* __restrict__ A,
    const float* __restrict__ wf, const float* __restrict__ wr,
    const float* __restrict__ bif, const float* __restrict__ bir,
    const float* __restrict__ bhf, const float* __restrict__ bhr,
    u16* __restrict__ xp)
{
  __shared__ u16 As[64][72];
  __shared__ u16 Bs[64][72];
  const int tid = threadIdx.x;
  const int n0  = blockIdx.x * 64;
  const int m0  = blockIdx.y * 64;
  const int dir = (n0 >= GG) ? 1 : 0;
  const int gb  = n0 - dir * GG;
  const float* W  = dir ? wr : wf;
  const float* BI = dir ? bir : bif;
  const float* BH = dir ? bhr : bhf;

  const int w = tid >> 6, l = tid & 63, q = l >> 4, r = l & 15;
  f32x4 acc[4] = {};

  for (int k0 = 0; k0 < CC; k0 += 64){
    #pragma unroll
    for (int i = 0; i < 2; ++i){
      int ch = tid + 256 * i;
      int row = ch >> 3, c8 = ch & 7;
      *(uint4*)&As[row][c8 * 8] =
          *(const uint4*)&A[(size_t)(m0 + row) * CC + k0 + c8 * 8];
    }
    #pragma unroll
    for (int i = 0; i < 4; ++i){
      int ch = tid + 256 * i;
      int row = ch >> 4, c4 = ch & 15;
      const float* s = &W[(size_t)(gb + row) * CC + k0 + c4 * 4];
      float4 fv = *(const float4*)s;
      unsigned p0 = (unsigned)f2bf(fv.x) | ((unsigned)f2bf(fv.y) << 16);
      unsigned p1 = (unsigned)f2bf(fv.z) | ((unsigned)f2bf(fv.w) << 16);
      *(uint2*)&Bs[row][c4 * 4] = make_uint2(p0, p1);
    }
    __syncthreads();
    #pragma unroll
    for (int kk = 0; kk < 2; ++kk){
      short8 a = *(const short8*)&As[w * 16 + r][kk * 32 + q * 8];
      #pragma unroll
      for (int nt = 0; nt < 4; ++nt){
        short8 b = *(const short8*)&Bs[nt * 16 + r][kk * 32 + q * 8];
        acc[nt] = __builtin_amdgcn_mfma_f32_16x16x32_bf16(a, b, acc[nt], 0, 0, 0);
      }
    }
    __syncthreads();
  }
  // epilogue: tile rows = 4t x 16 mrow; wave w = t-offset, C-row q*4+j = mrow.
  const int t  = ((m0 >> 4) & 511) + w;
  const int bb = m0 >> 13;
  const size_t tb = ((size_t)(dir * 4 + bb) * TT + t) * 3;
  #pragma unroll
  for (int a = 0; a < 2; ++a){
    const int colb = gb + a * 32;              // 32-aligned, no gi straddle
    const int gi   = colb >> 8;
    const int laner = (((colb & 255) >> 5) * 64) + q * 16 + r;
    const int gg0 = colb + r, gg1 = colb + 16 + r;
    const float b0v = BI[gg0] + (gg0 < 2 * HH ? BH[gg0] : 0.0f);
    const float b1v = BI[gg1] + (gg1 < 2 * HH ? BH[gg1] : 0.0f);
    ushort8 o;
    #pragma unroll
    for (int j = 0; j < 4; ++j){
      o[j]     = f2bf(acc[a * 2][j]     + b0v);
      o[j + 4] = f2bf(acc[a * 2 + 1][j] + b1v);
    }
    *(ushort8*)&xp[((tb + gi) * 512 + laner) * 8] = o;
  }
}

// ---------------------------------------------------------------------------
// 3/5) recurrence. grid=8 (dir*4+bb), 512 threads. Wave wv owns h-cols
// [32wv,32wv+32) for all 3 gates. xp consumed straight from registers.
// ---------------------------------------------------------------------------
template<int OUT_F32>
__global__ __launch_bounds__(512, 2) void k_rec(const u16* __restrict__ xp,
    const float* __restrict__ whf, const float* __restrict__ whr,
    const float* __restrict__ bhf, const float* __restrict__ bhr,
    void* __restrict__ yout)
{
  __shared__ u16 hl[2][16][264];
  const int tid = threadIdx.x;
  const int d  = blockIdx.x >> 2, bb = blockIdx.x & 3;
  const int wv = tid >> 6, l = tid & 63, q = l >> 4, r = l & 15;
  const float* WH = d ? whr : whf;
  const float* BH = d ? bhr : bhf;
  const int b0 = bb * 16;

  // persistent W_hh B-fragments (bf16): lane gives B[k=kk*32+q*8+e][g=colb+r]
  short8 Bf[3][2][8];
  #pragma unroll
  for (int gi = 0; gi < 3; ++gi)
    #pragma unroll
    for (int ct = 0; ct < 2; ++ct){
      int g = gi * HH + wv * 32 + ct * 16 + r;
      #pragma unroll
      for (int kk = 0; kk < 8; ++kk){
        const float* s = &WH[(size_t)g * HH + kk * 32 + q * 8];
        float4 f0 = *(const float4*)s;
        float4 f1 = *(const float4*)(s + 4);
        short8 f;
        f[0]=(short)f2bf(f0.x); f[1]=(short)f2bf(f0.y);
        f[2]=(short)f2bf(f0.z); f[3]=(short)f2bf(f0.w);
        f[4]=(short)f2bf(f1.x); f[5]=(short)f2bf(f1.y);
        f[6]=(short)f2bf(f1.z); f[7]=(short)f2bf(f1.w);
        Bf[gi][ct][kk] = f;
      }
    }
  float bn[2];
  #pragma unroll
  for (int ct = 0; ct < 2; ++ct) bn[ct] = BH[2 * HH + wv * 32 + ct * 16 + r];

  float ho[2][4] = {};

  for (int i = tid; i < 16 * 264; i += 512) ((u16*)hl)[i] = 0;   // hl[0] only

  const int t0 = d ? (TT - 1) : 0;
  const int dstep = d ? -1 : 1;
  const ptrdiff_t pxstep = (ptrdiff_t)dstep * 3 * 512 * 8;       // u16 units

  const u16* px = xp + (((size_t)(d * 4 + bb) * TT + t0) * 3 * 512 + tid) * 8;

  ushort8 cxA[3], cxB[3];
  cxA[0] = *(const ushort8*)(px);
  cxA[1] = *(const ushort8*)(px + 4096);
  cxA[2] = *(const ushort8*)(px + 8192);
  px += pxstep;

  // per-lane output pointers
  u16*   py = nullptr;
  float* pf0 = nullptr; float* pf1 = nullptr; float* pf2 = nullptr; float* pf3 = nullptr;
  if (OUT_F32){
    float* yf = (float*)yout;
    size_t base = (size_t)d * HH + wv * 32 + r;
    pf0 = yf + (((size_t)(b0 + q * 4 + 0) * TT + t0) * (2 * HH)) + base;
    pf1 = yf + (((size_t)(b0 + q * 4 + 1) * TT + t0) * (2 * HH)) + base;
    pf2 = yf + (((size_t)(b0 + q * 4 + 2) * TT + t0) * (2 * HH)) + base;
    pf3 = yf + (((size_t)(b0 + q * 4 + 3) * TT + t0) * (2 * HH)) + base;
  } else {
    u16* yb = (u16*)yout;
    py = yb + (((size_t)bb * TT + t0) * 16 + q * 4) * 512 + (size_t)d * HH + wv * 32 + r;
  }
  const ptrdiff_t pystep = (ptrdiff_t)dstep * 16 * 512;   // u16 (row' layout)
  const ptrdiff_t pfstep = (ptrdiff_t)dstep * 2 * HH;     // f32 ([b][t][512])

  __syncthreads();

  auto step = [&](int s, int cur, ushort8* cxu, ushort8* cxl) {
    const int nxt = cur ^ 1;
    // (1) issue next step's xp loads (in flight across the whole step+barrier)
    cxl[0] = *(const ushort8*)(px);
    cxl[1] = *(const ushort8*)(px + 4096);
    cxl[2] = *(const ushort8*)(px + 8192);
    if (s < TT - 2) px += pxstep;

    // (2+3) per-ct: MFMA then gates
    #pragma unroll
    for (int ct = 0; ct < 2; ++ct){
      f32x4 a0 = {0.f,0.f,0.f,0.f}, a1 = {0.f,0.f,0.f,0.f};
      f32x4 a2 = {bn[ct],bn[ct],bn[ct],bn[ct]};
      #pragma unroll
      for (int kk = 0; kk < 8; ++kk){
        short8 af = *(const short8*)&hl[cur][r][kk * 32 + q * 8];
        a0 = __builtin_amdgcn_mfma_f32_16x16x32_bf16(af, Bf[0][ct][kk], a0, 0, 0, 0);
        a1 = __builtin_amdgcn_mfma_f32_16x16x32_bf16(af, Bf[1][ct][kk], a1, 0, 0, 0);
        a2 = __builtin_amdgcn_mfma_f32_16x16x32_bf16(af, Bf[2][ct][kk], a2, 0, 0, 0);
      }
      const int col = wv * 32 + ct * 16 + r;
      #pragma unroll
      for (int j = 0; j < 4; ++j){
        float xr = bf2f(cxu[0][ct * 4 + j]);
        float xz = bf2f(cxu[1][ct * 4 + j]);
        float xn = bf2f(cxu[2][ct * 4 + j]);
        float er = __expf(-(xr + a0[j]));
        float ez = __expf(-(xz + a1[j]));
        float sr = 1.0f + er, sz = 1.0f + ez;
        float R  = __builtin_amdgcn_rcpf(sr * sz);
        float rr = sz * R;                       // sigmoid(xr+ar)
        float zz = sr * R;                       // sigmoid(xz+az)
        float ni = xn + rr * a2[j];
        float e2 = __expf(-2.0f * ni);
        float nn = 2.0f * __builtin_amdgcn_rcpf(1.0f + e2) - 1.0f;  // tanh(ni)
        float h0 = ho[ct][j];
        float hn = nn + zz * (h0 - nn);
        ho[ct][j] = hn;
        u16 hb = f2bf(hn);
        hl[nxt][q * 4 + j][col] = hb;
        if (OUT_F32){
          float* pf = (j == 0) ? pf0 : (j == 1) ? pf1 : (j == 2) ? pf2 : pf3;
          pf[ct * 16] = hn;
        } else {
          py[j * 512 + ct * 16] = hb;
        }
      }
    }
    // (4) advance y pointers (uniform scalar deltas)
    if (OUT_F32){ pf0 += pfstep; pf1 += pfstep; pf2 += pfstep; pf3 += pfstep; }
    else        { py  += pystep; }

    // (5) barrier: drain LDS writes only; xp loads stay in flight
    asm volatile("s_waitcnt lgkmcnt(0)" ::: "memory");
    __builtin_amdgcn_s_barrier();
    asm volatile("" ::: "memory");
  };

  #pragma unroll 1
  for (int s = 0; s < TT; s += 2){
    step(s,     0, cxA, cxB);
    step(s + 1, 1, cxB, cxA);
  }
}

// ---------------------------------------------------------------------------
extern "C" void kernel_launch(void* const* d_in, const int* in_sizes, int n_in,
                              void* d_out, int out_size, void* d_ws, size_t ws_size,
                              hipStream_t stream)
{
  const float* x        = (const float*)d_in[0];
  const float* w_ih_l0f = (const float*)d_in[1];
  const float* w_hh_l0f = (const float*)d_in[2];
  const float* b_ih_l0f = (const float*)d_in[3];
  const float* b_hh_l0f = (const float*)d_in[4];
  const float* w_ih_l0r = (const float*)d_in[5];
  const float* w_hh_l0r = (const float*)d_in[6];
  const float* b_ih_l0r = (const float*)d_in[7];
  const float* b_hh_l0r = (const float*)d_in[8];
  const float* w_ih_l1f = (const float*)d_in[9];
  const float* w_hh_l1f = (const float*)d_in[10];
  const float* b_ih_l1f = (const float*)d_in[11];
  const float* b_hh_l1f = (const float*)d_in[12];
  const float* w_ih_l1r = (const float*)d_in[13];
  const float* w_hh_l1r = (const float*)d_in[14];
  const float* b_ih_l1r = (const float*)d_in[15];
  const float* b_hh_l1r = (const float*)d_in[16];

  u16* xT = (u16*)d_ws;                          // region A: row'-layout activations
  u16* xp = xT + (size_t)BB * TT * CC;           // region B: rec-native xp
  u16* y0 = xT;
  (void)in_sizes; (void)n_in; (void)out_size; (void)ws_size;

  k_transpose<<<dim3(TT / 32, CC / 32, BB), 256, 0, stream>>>(x, xT);

  k_gemm<<<dim3(2 * GG / 64, BB * TT / 64), 256, 0, stream>>>(
      xT, w_ih_l0f, w_ih_l0r, b_ih_l0f, b_ih_l0r, b_hh_l0f, b_hh_l0r, xp);

  k_rec<0><<<dim3(8), 512, 0, stream>>>(xp, w_hh_l0f, w_hh_l0r, b_hh_l0f, b_hh_l0r, (void*)y0);

  k_gemm<<<dim3(2 * GG / 64, BB * TT / 64), 256, 0, stream>>>(
      y0, w_ih_l1f, w_ih_l1r, b_ih_l1f, b_ih_l1r, b_hh_l1f, b_hh_l1r, xp);

  k_rec<1><<<dim3(8), 512, 0, stream>>>(xp, w_hh_l1f, w_hh_l1r, b_hh_l1f, b_hh_l1r, d_out);
}

// Round 5
// 1702.993 us; speedup vs baseline: 2.5256x; 1.3617x over previous
//
#include <hip/hip_runtime.h>

// ---------------------------------------------------------------------------
// 2-layer bidirectional GRU, H=256, C=512, T=512, B=64  (MI355X / gfx950)
//
// R4b: same as R4, with HIP vector-type name collision fixed (ushort4 ->
// u16x4, ushort8 -> u16x8).
//
// R4: recurrence spread over 16 WGs (dir x 8 batch-blocks of 8). MFMA runs
// M=8 on 16x16 tiles (rows 8-15 zero); the ct=1 accumulator tile is handed
// to the upper 32 lanes via permlane32_swap so every lane does gate math on
// 4 outputs (was 8). xp is stored PRE-SCALED (-log2e for r/z, -2log2e for n;
// W_n/b_hh_n pre-scaled too) so each exp arg is one FMA into v_exp_f32.
// bf16 packing via v_cvt_pk_bf16_f32.
//
// Activation row order ("row''"): row'' = ((b>>3)*512 + t)*8 + (b&7).
// xpA [d*8+bb8][t][lane 512][8 u16] = r0..r3,z0..z3 (pre-scaled bf16)
// xpB [d*8+bb8][t][lane 512][4 u16] = n0..n3        (pre-scaled bf16)
// ---------------------------------------------------------------------------

typedef unsigned short u16;
typedef __attribute__((ext_vector_type(8))) short short8;            // 8 bf16
typedef __attribute__((ext_vector_type(8))) unsigned short u16x8;
typedef __attribute__((ext_vector_type(4))) unsigned short u16x4;
typedef __attribute__((ext_vector_type(4))) float f32x4;

#define C1 (-1.4426950408889634f)   // -log2(e)
#define C2 (-2.8853900817779268f)   // -2*log2(e)

static __device__ __forceinline__ u16 f2bf(float x){
  union { float f; unsigned u; } v; v.f = x;
  unsigned r = v.u + 0x7fffu + ((v.u >> 16) & 1u);   // RNE
  return (u16)(r >> 16);
}
static __device__ __forceinline__ float bf2f(u16 b){
  union { float f; unsigned u; } v; v.u = ((unsigned)b) << 16;
  return v.f;
}
static __device__ __forceinline__ unsigned cvt_pk_bf16(float lo, float hi){
  unsigned d;
  asm("v_cvt_pk_bf16_f32 %0, %1, %2" : "=v"(d) : "v"(lo), "v"(hi));
  return d;
}
#if __has_builtin(__builtin_amdgcn_exp2f)
#define EXP2(x) __builtin_amdgcn_exp2f(x)
#else
#define EXP2(x) exp2f(x)
#endif
#define RCP(x) __builtin_amdgcn_rcpf(x)

// lanes >=32 receive x from lane-32; lanes <32 keep own x.
static __device__ __forceinline__ float half_bcast(float x){
#if __has_builtin(__builtin_amdgcn_permlane32_swap)
  auto v = __builtin_amdgcn_permlane32_swap(__float_as_uint(x), __float_as_uint(x), 0, 0);
  return __uint_as_float(v[0]);
#else
  return __shfl_xor(x, 32, 64);
#endif
}

#define TT 512
#define BB 64
#define HH 256
#define GG 768
#define CC 512

// ---------------------------------------------------------------------------
// 1) transpose + cast: x fp32 [B][C][T] -> xT bf16 [row''][C]
// ---------------------------------------------------------------------------
__global__ __launch_bounds__(256) void k_transpose(const float* __restrict__ x,
                                                   u16* __restrict__ xT)
{
  __shared__ u16 tile[32][33];
  const int b  = blockIdx.z;
  const int c0 = blockIdx.y * 32, t0 = blockIdx.x * 32;
  const int tx = threadIdx.x & 31, ty = threadIdx.x >> 5;
  const float* xb = x + (size_t)b * CC * TT;
  #pragma unroll
  for (int i = 0; i < 4; ++i){
    int c = c0 + ty + i * 8;
    tile[ty + i * 8][tx] = f2bf(xb[(size_t)c * TT + t0 + tx]);
  }
  __syncthreads();
  const int bb8 = b >> 3, mrow = b & 7;
  #pragma unroll
  for (int i = 0; i < 4; ++i){
    int t = t0 + ty + i * 8;
    size_t rowp = ((size_t)bb8 * TT + t) * 8 + mrow;
    xT[rowp * CC + c0 + tx] = tile[tx][ty + i * 8];
  }
}

// ---------------------------------------------------------------------------
// 2) GEMM: A[row''][k] (bf16) x W[g][k] (fp32->bf16) -> pre-scaled xpA/xpB
//    r,z: v = C1*(acc + b_ih + b_hh);  n: v = C2*(acc + b_ih)
// ---------------------------------------------------------------------------
__global__ __launch_bounds__(256) void k_gemm(const u16* __restrict__ A,
    const float* __restrict__ wf, const float* __restrict__ wr,
    const float* __restrict__ bif, const float* __restrict__ bir,
    const float* __restrict__ bhf, const float* __restrict__ bhr,
    u16* __restrict__ xpA, u16* __restrict__ xpB)
{
  __shared__ u16 As[64][72];
  __shared__ u16 Bs[64][72];
  const int tid = threadIdx.x;
  const int n0  = blockIdx.x * 64;
  const int m0  = blockIdx.y * 64;
  const int dir = (n0 >= GG) ? 1 : 0;
  const int gb  = n0 - dir * GG;
  const float* W  = dir ? wr : wf;
  const float* BI = dir ? bir : bif;
  const float* BH = dir ? bhr : bhf;

  const int w = tid >> 6, l = tid & 63, q = l >> 4, r = l & 15;
  f32x4 acc[4] = {};

  for (int k0 = 0; k0 < CC; k0 += 64){
    #pragma unroll
    for (int i = 0; i < 2; ++i){
      int ch = tid + 256 * i;
      int row = ch >> 3, c8 = ch & 7;
      *(uint4*)&As[row][c8 * 8] =
          *(const uint4*)&A[(size_t)(m0 + row) * CC + k0 + c8 * 8];
    }
    #pragma unroll
    for (int i = 0; i < 4; ++i){
      int ch = tid + 256 * i;
      int row = ch >> 4, c4 = ch & 15;
      const float* s = &W[(size_t)(gb + row) * CC + k0 + c4 * 4];
      float4 fv = *(const float4*)s;
      unsigned p0 = (unsigned)f2bf(fv.x) | ((unsigned)f2bf(fv.y) << 16);
      unsigned p1 = (unsigned)f2bf(fv.z) | ((unsigned)f2bf(fv.w) << 16);
      *(uint2*)&Bs[row][c4 * 4] = make_uint2(p0, p1);
    }
    __syncthreads();
    #pragma unroll
    for (int kk = 0; kk < 2; ++kk){
      short8 a = *(const short8*)&As[w * 16 + r][kk * 32 + q * 8];
      #pragma unroll
      for (int nt = 0; nt < 4; ++nt){
        short8 b = *(const short8*)&Bs[nt * 16 + r][kk * 32 + q * 8];
        acc[nt] = __builtin_amdgcn_mfma_f32_16x16x32_bf16(a, b, acc[nt], 0, 0, 0);
      }
    }
    __syncthreads();
  }
  // epilogue: scatter into rec-native pre-scaled layout.
  // C row (w*16+q*4+j) -> (bb8, t, mrow); C col (gb+nt*16+r) -> (gi, lane', jdx)
  #pragma unroll
  for (int nt = 0; nt < 4; ++nt){
    const int g  = gb + nt * 16 + r;
    const int gi = g >> 8;
    const int ch = g & 255;
    const int wvl = ch >> 5, cw = ch & 31;
    const int qm = cw >> 4, rp = cw & 15;
    const float bias = (gi < 2) ? (BI[g] + BH[g]) : BI[g];
    const float sc   = (gi < 2) ? C1 : C2;
    #pragma unroll
    for (int j = 0; j < 4; ++j){
      const int row  = m0 + w * 16 + q * 4 + j;
      const int t    = (row >> 3) & 511;
      const int bb8  = row >> 12;
      const int mrow = row & 7;
      const int lane = wvl * 64 + (qm * 2 + (mrow >> 2)) * 16 + rp;
      const int jdx  = mrow & 3;
      const size_t base = ((size_t)(dir * 8 + bb8) * TT + t) * 512 + lane;
      const u16 v = f2bf(sc * (acc[nt][j] + bias));
      if (gi < 2) xpA[base * 8 + gi * 4 + jdx] = v;
      else        xpB[base * 4 + jdx]          = v;
    }
  }
}

// ---------------------------------------------------------------------------
// 3/5) recurrence. grid=16 (d*8+bb8), 512 threads. Wave wv owns h-cols
// [32wv,32wv+32) for all 3 gates; M=8 batch rows. Lanes l<32 handle ct=0,
// lanes l>=32 handle ct=1 via half_bcast of the acc tiles.
// ---------------------------------------------------------------------------
template<int OUT_F32>
__global__ __launch_bounds__(512, 2) void k_rec(
    const u16* __restrict__ xpA, const u16* __restrict__ xpB,
    const float* __restrict__ whf, const float* __restrict__ whr,
    const float* __restrict__ bhf, const float* __restrict__ bhr,
    void* __restrict__ yout)
{
  __shared__ u16 hl[2][16][264];     // rows 8-15 stay zero (M=8)
  const int tid = threadIdx.x;
  const int d = blockIdx.x >> 3, bb8 = blockIdx.x & 7;
  const int wv = tid >> 6, l = tid & 63, q = l >> 4, r = l & 15;
  const int upper = (l >= 32);       // handles ct=1
  const float* WH = d ? whr : whf;
  const float* BH = d ? bhr : bhf;

  // persistent W_hh B-fragments; gi==2 (n-gate) pre-scaled by C2.
  short8 Bf[3][2][8];
  #pragma unroll
  for (int gi = 0; gi < 3; ++gi){
    const float sc = (gi == 2) ? C2 : 1.0f;
    #pragma unroll
    for (int ct = 0; ct < 2; ++ct){
      int g = gi * HH + wv * 32 + ct * 16 + r;
      #pragma unroll
      for (int kk = 0; kk < 8; ++kk){
        const float* s = &WH[(size_t)g * HH + kk * 32 + q * 8];
        float4 f0 = *(const float4*)s;
        float4 f1 = *(const float4*)(s + 4);
        short8 f;
        f[0]=(short)f2bf(f0.x*sc); f[1]=(short)f2bf(f0.y*sc);
        f[2]=(short)f2bf(f0.z*sc); f[3]=(short)f2bf(f0.w*sc);
        f[4]=(short)f2bf(f1.x*sc); f[5]=(short)f2bf(f1.y*sc);
        f[6]=(short)f2bf(f1.z*sc); f[7]=(short)f2bf(f1.w*sc);
        Bf[gi][ct][kk] = f;
      }
    }
  }
  float bnp[2];                      // C2*b_hh_n for ct=0,1 (travels with acc)
  #pragma unroll
  for (int ct = 0; ct < 2; ++ct) bnp[ct] = C2 * BH[2 * HH + wv * 32 + ct * 16 + r];

  const int col  = wv * 32 + (upper ? 16 : 0) + r;   // this lane's h-col
  const int rowb = (q & 1) * 4;                      // this lane's first row
  float ho[4] = {};

  for (int i = tid; i < 2 * 16 * 264; i += 512) ((u16*)hl)[i] = 0;

  const int t0 = d ? (TT - 1) : 0;
  const int dstep = d ? -1 : 1;

  const size_t blk = (size_t)(d * 8 + bb8) * TT;
  const u16* pxA = xpA + ((blk + t0) * 512 + tid) * 8;
  const u16* pxB = xpB + ((blk + t0) * 512 + tid) * 4;
  const ptrdiff_t pxAs = (ptrdiff_t)dstep * 512 * 8;
  const ptrdiff_t pxBs = (ptrdiff_t)dstep * 512 * 4;

  struct XP { u16x8 a; u16x4 b; };
  XP cxA, cxB;
  cxA.a = *(const u16x8*)pxA;  cxA.b = *(const u16x4*)pxB;
  pxA += pxAs; pxB += pxBs;

  // output base pointers (this lane's row block)
  u16*   py = nullptr;  float* pf = nullptr;
  if (OUT_F32){
    float* yf = (float*)yout;
    pf = yf + (((size_t)(bb8 * 8 + rowb) * TT + t0) * (2 * HH)) + (size_t)d * HH + col;
  } else {
    u16* yb = (u16*)yout;
    py = yb + (((size_t)bb8 * TT + t0) * 8 + rowb) * 512 + (size_t)d * HH + col;
  }
  const ptrdiff_t pys = (ptrdiff_t)dstep * 8 * 512;       // u16, row''-layout
  const ptrdiff_t pfs = (ptrdiff_t)dstep * 2 * HH;        // f32, [b][t][512]

  __syncthreads();

  auto step = [&](int s, int cur, XP* cxu, XP* cxl) {
    const int nxt = cur ^ 1;
    // (1) issue next step's xp loads (stay in flight across the barrier)
    cxl->a = *(const u16x8*)pxA;
    cxl->b = *(const u16x4*)pxB;
    if (s < TT - 2){ pxA += pxAs; pxB += pxBs; }

    // (2) gh = h @ W^T for both ct tiles (M=8; rows 8-15 zero)
    f32x4 acc[3][2];
    #pragma unroll
    for (int ct = 0; ct < 2; ++ct){
      acc[0][ct] = (f32x4){0.f,0.f,0.f,0.f};
      acc[1][ct] = (f32x4){0.f,0.f,0.f,0.f};
      acc[2][ct] = (f32x4){bnp[ct],bnp[ct],bnp[ct],bnp[ct]};
    }
    #pragma unroll
    for (int kk = 0; kk < 8; ++kk){
      short8 af = *(const short8*)&hl[cur][r][kk * 32 + q * 8];
      #pragma unroll
      for (int gi = 0; gi < 3; ++gi){
        acc[gi][0] = __builtin_amdgcn_mfma_f32_16x16x32_bf16(af, Bf[gi][0][kk], acc[gi][0], 0, 0, 0);
        acc[gi][1] = __builtin_amdgcn_mfma_f32_16x16x32_bf16(af, Bf[gi][1][kk], acc[gi][1], 0, 0, 0);
      }
    }
    // (3) gates: 4 outputs/lane. upper lanes take ct=1 tiles via half_bcast.
    float hv[4];
    #pragma unroll
    for (int j = 0; j < 4; ++j){
      float s0 = half_bcast(acc[0][1][j]);
      float s1 = half_bcast(acc[1][1][j]);
      float s2 = half_bcast(acc[2][1][j]);
      float a0v = upper ? s0 : acc[0][0][j];
      float a1v = upper ? s1 : acc[1][0][j];
      float a2v = upper ? s2 : acc[2][0][j];
      float xrp = bf2f(cxu->a[j]);
      float xzp = bf2f(cxu->a[4 + j]);
      float xnp = bf2f(cxu->b[j]);
      float er = EXP2(fmaf(a0v, C1, xrp));       // e^-(xr+ar)
      float ez = EXP2(fmaf(a1v, C1, xzp));       // e^-(xz+az)
      float sr = 1.0f + er, sz = 1.0f + ez;
      float R  = RCP(sr * sz);
      float rr = sz * R;                          // sigmoid
      float zz = sr * R;
      float e2 = EXP2(fmaf(rr, a2v, xnp));        // e^-2ni (a2v,xnp pre-scaled)
      float nn = fmaf(2.0f, RCP(1.0f + e2), -1.0f);
      hv[j] = fmaf(zz, ho[j] - nn, nn);
      ho[j] = hv[j];
    }
    // (4) pack + store h (LDS) and y (global)
    unsigned p01 = cvt_pk_bf16(hv[0], hv[1]);
    unsigned p23 = cvt_pk_bf16(hv[2], hv[3]);
    hl[nxt][rowb + 0][col] = (u16)p01;
    hl[nxt][rowb + 1][col] = (u16)(p01 >> 16);
    hl[nxt][rowb + 2][col] = (u16)p23;
    hl[nxt][rowb + 3][col] = (u16)(p23 >> 16);
    if (OUT_F32){
      pf[0 * TT * 512] = hv[0];
      pf[1 * TT * 512] = hv[1];
      pf[2 * TT * 512] = hv[2];
      pf[3 * TT * 512] = hv[3];
      pf += pfs;
    } else {
      py[0 * 512] = (u16)p01;
      py[1 * 512] = (u16)(p01 >> 16);
      py[2 * 512] = (u16)p23;
      py[3 * 512] = (u16)(p23 >> 16);
      py += pys;
    }
    // (5) barrier: drain LDS only; global loads stay in flight
    asm volatile("s_waitcnt lgkmcnt(0)" ::: "memory");
    __builtin_amdgcn_s_barrier();
    asm volatile("" ::: "memory");
  };

  #pragma unroll 1
  for (int s = 0; s < TT; s += 2){
    step(s,     0, &cxA, &cxB);
    step(s + 1, 1, &cxB, &cxA);
  }
}

// ---------------------------------------------------------------------------
extern "C" void kernel_launch(void* const* d_in, const int* in_sizes, int n_in,
                              void* d_out, int out_size, void* d_ws, size_t ws_size,
                              hipStream_t stream)
{
  const float* x        = (const float*)d_in[0];
  const float* w_ih_l0f = (const float*)d_in[1];
  const float* w_hh_l0f = (const float*)d_in[2];
  const float* b_ih_l0f = (const float*)d_in[3];
  const float* b_hh_l0f = (const float*)d_in[4];
  const float* w_ih_l0r = (const float*)d_in[5];
  const float* w_hh_l0r = (const float*)d_in[6];
  const float* b_ih_l0r = (const float*)d_in[7];
  const float* b_hh_l0r = (const float*)d_in[8];
  const float* w_ih_l1f = (const float*)d_in[9];
  const float* w_hh_l1f = (const float*)d_in[10];
  const float* b_ih_l1f = (const float*)d_in[11];
  const float* b_hh_l1f = (const float*)d_in[12];
  const float* w_ih_l1r = (const float*)d_in[13];
  const float* w_hh_l1r = (const float*)d_in[14];
  const float* b_ih_l1r = (const float*)d_in[15];
  const float* b_hh_l1r = (const float*)d_in[16];

  u16* xT  = (u16*)d_ws;                              // 16.78M u16 (xT / y0)
  u16* xpA = xT  + (size_t)BB * TT * CC;              // 33.55M u16
  u16* xpB = xpA + (size_t)16 * TT * 512 * 8;         // 16.78M u16
  u16* y0  = xT;
  (void)in_sizes; (void)n_in; (void)out_size; (void)ws_size;

  k_transpose<<<dim3(TT / 32, CC / 32, BB), 256, 0, stream>>>(x, xT);

  k_gemm<<<dim3(2 * GG / 64, BB * TT / 64), 256, 0, stream>>>(
      xT, w_ih_l0f, w_ih_l0r, b_ih_l0f, b_ih_l0r, b_hh_l0f, b_hh_l0r, xpA, xpB);

  k_rec<0><<<dim3(16), 512, 0, stream>>>(xpA, xpB, w_hh_l0f, w_hh_l0r, b_hh_l0f, b_hh_l0r, (void*)y0);

  k_gemm<<<dim3(2 * GG / 64, BB * TT / 64), 256, 0, stream>>>(
      y0, w_ih_l1f, w_ih_l1r, b_ih_l1f, b_ih_l1r, b_hh_l1f, b_hh_l1r, xpA, xpB);

  k_rec<1><<<dim3(16), 512, 0, stream>>>(xpA, xpB, w_hh_l1f, w_hh_l1r, b_hh_l1f, b_hh_l1r, d_out);
}